// Round 16
// baseline (254.577 us; speedup 1.0000x reference)
//
#include <hip/hip_runtime.h>
#include <math.h>

#define ZB 16
#define NATOMS 192
#define NBAS 40
#define ZA (ZB*NATOMS)       // 3072
#define NKC 32               // K-chunks in contraction
#define TABN 4096            // R-table samples over u in [0,40]
#define TABSTRIDE 262208     // (TABN+1)*64 per layer

typedef __attribute__((ext_vector_type(4))) float f32x4;
typedef __attribute__((ext_vector_type(8))) short bf16x8;

__device__ __forceinline__ unsigned short f2bf(float x){
    union { float f; unsigned u; } v; v.f = x;
    unsigned r = v.u + 0x7FFFu + ((v.u >> 16) & 1u);
    return (unsigned short)(r >> 16);
}
__device__ __forceinline__ unsigned short f2bf_t(float x){
    union { float f; unsigned u; } v; v.f = x;
    return (unsigned short)(v.u >> 16);
}
__device__ __forceinline__ float bf2f(unsigned short u){
    union { unsigned u; float f; } v; v.u = ((unsigned)u) << 16; return v.f;
}
__device__ __forceinline__ float bits2f(unsigned u){
    union { unsigned u; float f; } v; v.u = u; return v.f;
}
__device__ __forceinline__ unsigned f2bits(float x){
    union { float f; unsigned u; } v; v.f = x; return v.u;
}
__device__ __forceinline__ float sspf_lean(float x){
    float e = __builtin_amdgcn_exp2f(7.2134752f*x);
    float l = __builtin_amdgcn_logf(1.f + e);
    return fmaf(l, 0.13862944f, -0.13862944f);
}
__device__ __forceinline__ float spf_act(float x){
    float t = 7.2134752f*x;
    float tc = fminf(t, 126.f);
    float e = __builtin_amdgcn_exp2f(tc);
    float l = __builtin_amdgcn_logf(1.f + e);
    float r = l*0.13862944f;
    return (t > 126.f) ? x : r;
}

// ---------------- prep: Bp[layer][(j*64+h)*64 + i] = bf16(rWo[h][j][i]) — both layers
__global__ void k_prep(const float* __restrict__ rWo_0, const float* __restrict__ rWo_1,
                       unsigned short* __restrict__ Bp){
    int idx = blockIdx.x*256 + threadIdx.x;
    for (int i = idx; i < 2*262144; i += gridDim.x*256){
        int l = i >> 18, r = i & 262143;
        int n = r >> 6, ii = r & 63;       // n = j*64+h
        int j = n >> 6, h = n & 63;
        const float* src = l ? rWo_1 : rWo_0;
        Bp[i] = f2bf(src[(h*64 + j)*64 + ii]);
    }
}

// ---------------- R-table: Rtab[l][i*64+h] = bf16(R(u_i)[h]), u_i = i*(40/4096).
// Full-precision fp32 radial MLP per sample (more accurate than per-pair bf16 h2 MFMA).
__global__ void k_table(const float* __restrict__ rW1_0, const float* __restrict__ rb1_0,
                        const float* __restrict__ rW2_0, const float* __restrict__ rb2_0,
                        const float* __restrict__ rW1_1, const float* __restrict__ rb1_1,
                        const float* __restrict__ rW2_1, const float* __restrict__ rb2_1,
                        unsigned short* __restrict__ Rtab){
    __shared__ float h1S[64];
    int i = blockIdx.x;            // [0, 4097)
    int l = blockIdx.y;
    int h = threadIdx.x;           // 64
    const float* rW1 = l ? rW1_1 : rW1_0;
    const float* rb1 = l ? rb1_1 : rb1_0;
    const float* rW2 = l ? rW2_1 : rW2_0;
    const float* rb2 = l ? rb2_1 : rb2_0;
    float u = (float)i * 0.009765625f;          // 40/4096
    int k0 = (int)u;
    float fr = u - (float)k0;
    float cs = __cosf(fr * 1.57079632679489662f);
    float c0 = cs*cs, c1 = 1.f - c0;
    if (k0   >= NBAS) c0 = 0.f;
    if (k0+1 >= NBAS) c1 = 0.f;
    int kk0 = min(k0, NBAS-1)*64, kk1 = min(k0+1, NBAS-1)*64;
    h1S[h] = sspf_lean(c0*rW1[kk0+h] + c1*rW1[kk1+h] + rb1[h]);
    __syncthreads();
    float acc = rb2[h];
    #pragma unroll 8
    for (int hin = 0; hin < 64; hin++) acc += h1S[hin]*rW2[hin*64 + h];
    Rtab[(size_t)l*TABSTRIDE + i*64 + h] = f2bf(sspf_lean(acc));
}

// ---------------- tmp GEMM bf16 MFMA: Tg[m][s*4096 + j*64 + h] = (f_s[m] @ rWo[h][j][:]) * mask*c
__global__ __launch_bounds__(256,2) void k_tmpB(
    const unsigned short* __restrict__ fb, const unsigned short* __restrict__ fc,
    const float* __restrict__ feat,
    const float* __restrict__ Wb, const float* __restrict__ bb,
    const float* __restrict__ Wc, const float* __restrict__ bc,
    const float* __restrict__ mask, const unsigned short* __restrict__ Bp,
    unsigned short* __restrict__ Tg)
{
    __shared__ unsigned short sm[18432];   // As[128*72] | Bs[128*72]; Cs overlays all
    __shared__ float msk[128];
    __shared__ float featS[128*8];
    __shared__ float WbS[7*64];
    __shared__ float bbS[64], WcS[64], bcS[64];
    unsigned short* As = sm;
    unsigned short* Bs = sm + 9216;
    unsigned short* Cs = sm;

    int tid = threadIdx.x;
    int m0 = blockIdx.x*128, n0 = blockIdx.y*128, s = blockIdx.z;
    int lane = tid & 63, w = tid >> 6, q = lane >> 4, l15 = lane & 15;
    int wm = w & 1, wn = w >> 1;

    if (feat){
        #pragma unroll
        for (int it = 0; it < 4; it++){
            int idx = tid + it*256;            // 1024 floats
            featS[idx] = feat[(size_t)m0*8 + idx];
        }
        for (int i = tid; i < 448; i += 256) WbS[i] = Wb[i];   // 7x64, strided
        if (tid < 64){ bbS[tid] = bb[tid]; WcS[tid] = Wc[tid]; bcS[tid] = bc[tid]; }
        __syncthreads();
        #pragma unroll
        for (int it = 0; it < 32; it++){
            int idx = tid + it*256;            // 8192
            int r = idx >> 6, e = idx & 63;
            float acc;
            if (s == 0){
                acc = bbS[e];
                #pragma unroll
                for (int c = 0; c < 7; c++) acc += featS[r*8+c]*WbS[c*64+e];
            } else {
                acc = bcS[e] + featS[r*8+7]*WcS[e];
            }
            As[r*72 + e] = f2bf(acc);
        }
    } else {
        const unsigned short* f = s ? fc : fb;
        #pragma unroll
        for (int it = 0; it < 4; it++){
            int idx = tid + it*256;            // 1024 uint4
            int r = idx >> 3, c8 = idx & 7;
            *(uint4*)(As + r*72 + c8*8) = *(const uint4*)(f + (size_t)(m0 + r)*64 + c8*8);
        }
    }
    // B-staging: pure uint4 copies from pre-converted Bp rows
    #pragma unroll
    for (int it = 0; it < 4; it++){
        int idx = tid + it*256;                // 1024 uint4
        int r = idx >> 3, c8 = idx & 7;
        *(uint4*)(Bs + r*72 + c8*8) = *(const uint4*)(Bp + (size_t)(n0 + r)*64 + c8*8);
    }
    if (tid < 128) msk[tid] = mask[m0 + tid] * 0.07216878364870322f;
    __syncthreads();

    f32x4 acc[16];
    #pragma unroll
    for (int i = 0; i < 16; i++) acc[i] = (f32x4){0.f,0.f,0.f,0.f};
    #pragma unroll
    for (int kc = 0; kc < 2; kc++){
        bf16x8 af[4];
        #pragma unroll
        for (int mt = 0; mt < 4; mt++)
            af[mt] = *(const bf16x8*)(As + (wm*64 + mt*16 + l15)*72 + kc*32 + q*8);
        #pragma unroll
        for (int nt = 0; nt < 4; nt++){
            bf16x8 bf_ = *(const bf16x8*)(Bs + (wn*64 + nt*16 + l15)*72 + kc*32 + q*8);
            #pragma unroll
            for (int mt = 0; mt < 4; mt++)
                acc[mt*4+nt] = __builtin_amdgcn_mfma_f32_16x16x32_bf16(af[mt], bf_, acc[mt*4+nt], 0, 0, 0);
        }
    }
    __syncthreads();   // all As/Bs reads done -> overlay Cs
    #pragma unroll
    for (int mt = 0; mt < 4; mt++)
        #pragma unroll
        for (int nt = 0; nt < 4; nt++)
            #pragma unroll
            for (int e = 0; e < 4; e++){
                int row2 = mt*16 + q*4 + e;
                float v = acc[mt*4+nt][e] * msk[wm*64 + row2];
                Cs[w*4608 + row2*72 + nt*16 + l15] = f2bf_t(v);
            }
    __syncthreads();
    #pragma unroll
    for (int it = 0; it < 8; it++){
        int flat = lane + it*64;               // [0,512)
        int rr = flat >> 3, c8 = flat & 7;
        uint4 v = *(const uint4*)(Cs + w*4608 + rr*72 + c8*8);
        size_t dst = (size_t)(m0 + wm*64 + rr)*8192 + s*4096 + n0 + wn*64 + c8*8;
        *(uint4*)(Tg + dst) = v;
    }
}

// ---------------- FUSED contraction with table-interpolated R. Grid (ZB, NKC=32).
// Per b: per-lane r -> idx/frac -> two 16B gathers from Rtab -> lerp -> A-frag -> MFMA.
// No radial MLP in the hot loop. Double-buffered smB; epilogue staging overlays smB.
__global__ __launch_bounds__(256,2) void k_fused(
    const float* __restrict__ geom,
    const unsigned short* __restrict__ Rtab,
    const unsigned short* __restrict__ Tc,
    unsigned short* __restrict__ part)
{
    __shared__ unsigned short smB[2][128*72];   // 36864 B (epilogue staging reuses this)

    int tid = threadIdx.x;
    int z = blockIdx.x, kc = blockIdx.y;
    int lane = tid & 63, w = tid >> 6, q = lane >> 4, l15 = lane & 15;
    int a_r = tid >> 3, c8 = tid & 7;

    float gaxr[3], gayr[3], gazr[3];
    #pragma unroll
    for (int mt = 0; mt < 3; mt++){
        int ar = w*48 + mt*16 + l15;
        const float* gp = geom + (size_t)(z*NATOMS + ar)*3;
        gaxr[mt] = gp[0]; gayr[mt] = gp[1]; gazr[mt] = gp[2];
    }

    const size_t Tbase = (size_t)z*NATOMS*8192;
    uint4 rbv[4];
    {
        const unsigned short* Bb = Tc + Tbase + (size_t)(kc*6)*8192;
        #pragma unroll
        for (int r = 0; r < 4; r++) rbv[r] = *(const uint4*)(Bb + (size_t)(a_r + 32*r)*64 + c8*8);
    }

    f32x4 acc[24];
    #pragma unroll
    for (int i = 0; i < 24; i++) acc[i] = (f32x4){0.f,0.f,0.f,0.f};

    for (int i = 0; i < 6; i++){
        int buf = i & 1;
        int b = kc*6 + i;
        // commit prefetched B tile (buf last read in contraction(i-2), before barrier(i-1))
        #pragma unroll
        for (int r = 0; r < 4; r++) *(uint4*)(smB[buf] + (a_r + 32*r)*72 + c8*8) = rbv[r];
        if (i < 5){
            const unsigned short* Bb = Tc + Tbase + (size_t)(b+1)*8192;
            #pragma unroll
            for (int r = 0; r < 4; r++) rbv[r] = *(const uint4*)(Bb + (size_t)(a_r + 32*r)*64 + c8*8);
        }
        // per-lane table coords for this lane's 3 rows
        const float* gb = geom + (size_t)(z*NATOMS + b)*3;
        float gbx = gb[0], gby = gb[1], gbz = gb[2];
        int idxr[3]; float frr[3];
        #pragma unroll
        for (int mt = 0; mt < 3; mt++){
            float dx = gaxr[mt]-gbx, dy = gayr[mt]-gby, dz = gazr[mt]-gbz;
            float r = sqrtf(dx*dx + dy*dy + dz*dz);
            float fu = fminf(r * 399.36f, 4095.999f);   // r*3.9*102.4, clamped
            int id = (int)fu;
            frr[mt] = fu - (float)id;
            idxr[mt] = id*64;
        }
        // issue all table gathers (L2-resident; overlap with barrier wait)
        uint4 lo[2][3], hi[2][3];
        #pragma unroll
        for (int kq = 0; kq < 2; kq++)
            #pragma unroll
            for (int mt = 0; mt < 3; mt++){
                lo[kq][mt] = *(const uint4*)(Rtab + idxr[mt] + kq*32 + q*8);
                hi[kq][mt] = *(const uint4*)(Rtab + idxr[mt] + 64 + kq*32 + q*8);
            }
        __syncthreads();       // smB[buf] visible to all waves
        #pragma unroll
        for (int kq = 0; kq < 2; kq++){
            #pragma unroll
            for (int mt = 0; mt < 3; mt++){
                const unsigned* lp = (const unsigned*)&lo[kq][mt];
                const unsigned* hp = (const unsigned*)&hi[kq][mt];
                float fr = frr[mt];
                uint4 af_u;
                unsigned* ap = (unsigned*)&af_u;
                #pragma unroll
                for (int d = 0; d < 4; d++){
                    float a0 = bits2f(lp[d] << 16);
                    float a1 = bits2f(lp[d] & 0xffff0000u);
                    float b0 = bits2f(hp[d] << 16);
                    float b1 = bits2f(hp[d] & 0xffff0000u);
                    float v0 = fmaf(fr, b0 - a0, a0);
                    float v1 = fmaf(fr, b1 - a1, a1);
                    ap[d] = (f2bits(v0) >> 16) | (f2bits(v1) & 0xffff0000u);
                }
                bf16x8 af = *(bf16x8*)&af_u;
                #pragma unroll
                for (int nt = 0; nt < 8; nt++){
                    bf16x8 bb = *(const bf16x8*)(smB[buf] + (nt*16 + l15)*72 + kq*32 + q*8);
                    acc[mt*8+nt] = __builtin_amdgcn_mfma_f32_16x16x32_bf16(af, bb, acc[mt*8+nt], 0, 0, 0);
                }
            }
        }
    }
    // epilogue: LDS-staged contiguous write of part tile (192x128 bf16), staging over smB
    unsigned short* stg = (unsigned short*)smB;   // row stride 136 shorts (26112 B <= 36864)
    #pragma unroll
    for (int half = 0; half < 2; half++){
        __syncthreads();
        if ((w >> 1) == half){
            int wl = w & 1;
            #pragma unroll
            for (int mt = 0; mt < 3; mt++)
                #pragma unroll
                for (int nt = 0; nt < 8; nt++)
                    #pragma unroll
                    for (int e = 0; e < 4; e++){
                        int row = wl*48 + mt*16 + q*4 + e;      // [0,96)
                        stg[row*136 + nt*16 + l15] = f2bf_t(acc[mt*8+nt][e]);
                    }
        }
        __syncthreads();
        unsigned short* gdst = part + ((size_t)(z*NKC + kc)*NATOMS + half*96)*128;
        #pragma unroll
        for (int it = 0; it < 6; it++){
            int flat = tid + it*256;          // [0,1536) uint4s
            int row = flat >> 4, cc = flat & 15;
            uint4 v = *(const uint4*)(stg + row*136 + cc*8);
            *(uint4*)(gdst + row*128 + cc*8) = v;
        }
    }
}

// ---------------- reduce partials + sp + mask -> bf16 next features (layer 0 only)
__global__ void k_reduceB(const unsigned short* __restrict__ part, const float* __restrict__ mask,
                          unsigned short* __restrict__ fb, unsigned short* __restrict__ fc){
    int zl = blockIdx.y;
    int idx = blockIdx.x*256 + threadIdx.x;    // [0, 24576)
    int a = idx >> 7, j2 = idx & 127;
    const unsigned short* p = part + ((size_t)(zl*NKC)*NATOMS + a)*128 + j2;
    float s = 0.f;
    #pragma unroll
    for (int c = 0; c < NKC; c++) s += bf2f(p[(size_t)c*NATOMS*128]);
    int rowg = zl*NATOMS + a;
    float v = spf_act(s) * mask[rowg];
    if (j2 < 64) fb[rowg*64 + j2] = f2bf(v);
    else         fc[rowg*64 + j2 - 64] = f2bf(v);
}

// ---------------- fused tail: reduce(layer1) + sp + mask + h1 + BN1 + leaky + h2 + BN2
// + leaky + mask + atom-sum (atomicAdd into zeroed out). One block per atom, 512 thr.
__global__ __launch_bounds__(512) void k_head2(
    const unsigned short* __restrict__ part, const float* __restrict__ mask,
    const float* __restrict__ fW1, const float* __restrict__ fb1,
    const float* __restrict__ fW2, const float* __restrict__ fb2,
    float* __restrict__ out)
{
    __shared__ float X[2048];
    __shared__ float red[16];
    __shared__ float stats[2];
    int a = blockIdx.x, tid = threadIdx.x;     // 512 threads = 8 waves
    int lane = tid & 63, w = tid >> 6;

    // reduce part over kc -> features X[z*128 + j2]
    #pragma unroll
    for (int i = 0; i < 4; i++){
        int idx = tid + i*512; int z = idx >> 7, j2 = idx & 127;
        const unsigned short* p = part + ((size_t)(z*NKC)*NATOMS + a)*128 + j2;
        float s = 0.f;
        #pragma unroll
        for (int c = 0; c < NKC; c++) s += bf2f(p[(size_t)c*NATOMS*128]);
        X[idx] = spf_act(s) * mask[z*NATOMS + a];
    }
    __syncthreads();
    // h1: one float4 output per thread (512 x 4 = 2048)
    f32x4 v; float s, ss;
    {
        int z = tid >> 5, k4 = (tid & 31)*4;
        f32x4 acc = { fb1[k4], fb1[k4+1], fb1[k4+2], fb1[k4+3] };
        #pragma unroll 4
        for (int c = 0; c < 128; c++){
            float xv = X[z*128 + c];
            float4 wv = *(const float4*)(fW1 + (size_t)c*128 + k4);
            acc[0] += xv*wv.x; acc[1] += xv*wv.y; acc[2] += xv*wv.z; acc[3] += xv*wv.w;
        }
        v = acc;
        s = acc[0]+acc[1]+acc[2]+acc[3];
        ss = acc[0]*acc[0]+acc[1]*acc[1]+acc[2]*acc[2]+acc[3]*acc[3];
    }
    for (int off = 32; off; off >>= 1){ s += __shfl_down(s, off); ss += __shfl_down(ss, off); }
    if (!lane){ red[w] = s; red[8+w] = ss; }
    __syncthreads();
    if (!tid){
        float S = 0.f, SS = 0.f;
        #pragma unroll
        for (int i = 0; i < 8; i++){ S += red[i]; SS += red[8+i]; }
        float m = S*(1.f/2048.f), var = SS*(1.f/2048.f) - m*m;
        stats[0] = m; stats[1] = rsqrtf(var + 1e-5f);
    }
    __syncthreads();
    float m1 = stats[0], inv1 = stats[1];
    {
        f32x4 t;
        #pragma unroll
        for (int e = 0; e < 4; e++){
            float x = (v[e]-m1)*inv1;
            t[e] = (x > 0.f) ? x : 0.2f*x;
        }
        *(f32x4*)(X + tid*4) = t;
    }
    __syncthreads();
    // h2: one output per thread (512)
    float u;
    {
        int z = tid >> 5, j = tid & 31;
        float acc = fb2[j];
        #pragma unroll 8
        for (int k = 0; k < 128; k++) acc += X[z*128 + k]*fW2[k*32 + j];
        u = acc; s = acc; ss = acc*acc;
    }
    for (int off = 32; off; off >>= 1){ s += __shfl_down(s, off); ss += __shfl_down(ss, off); }
    if (!lane){ red[w] = s; red[8+w] = ss; }
    __syncthreads();
    if (!tid){
        float S = 0.f, SS = 0.f;
        #pragma unroll
        for (int i = 0; i < 8; i++){ S += red[i]; SS += red[8+i]; }
        float m = S*(1.f/512.f), var = SS*(1.f/512.f) - m*m;
        stats[0] = m; stats[1] = rsqrtf(var + 1e-5f);
    }
    __syncthreads();
    float m2 = stats[0], inv2 = stats[1];
    {
        int z = tid >> 5, j = tid & 31;
        float x = (u-m2)*inv2;
        x = (x > 0.f) ? x : 0.2f*x;
        x *= mask[z*NATOMS + a];
        atomicAdd(&out[z*32 + j], x);
    }
}

extern "C" void kernel_launch(void* const* d_in, const int* in_sizes, int n_in,
                              void* d_out, int out_size, void* d_ws, size_t ws_size,
                              hipStream_t stream){
    const float* features = (const float*)d_in[0];
    const float* geometry = (const float*)d_in[1];
    const float* mask     = (const float*)d_in[2];
    const float* W_bio    = (const float*)d_in[3];
    const float* b_bio    = (const float*)d_in[4];
    const float* W_ch     = (const float*)d_in[5];
    const float* b_ch     = (const float*)d_in[6];
    const float* rW1[2] = {(const float*)d_in[7],  (const float*)d_in[12]};
    const float* rb1[2] = {(const float*)d_in[8],  (const float*)d_in[13]};
    const float* rW2[2] = {(const float*)d_in[9],  (const float*)d_in[14]};
    const float* rb2[2] = {(const float*)d_in[10], (const float*)d_in[15]};
    const float* rWo[2] = {(const float*)d_in[11], (const float*)d_in[16]};
    const float* fW1 = (const float*)d_in[17];
    const float* fb1 = (const float*)d_in[18];
    const float* fW2 = (const float*)d_in[19];
    const float* fb2 = (const float*)d_in[20];

    char* ws = (char*)d_ws;
    unsigned short* fAb = (unsigned short*)ws;   ws += (size_t)ZA*64*2;
    unsigned short* fAc = (unsigned short*)ws;   ws += (size_t)ZA*64*2;
    unsigned short* Rtab = (unsigned short*)ws;  ws += (size_t)2*TABSTRIDE*2;        // 1.05 MB
    unsigned short* Bp = (unsigned short*)ws;    ws += (size_t)2*262144*2;           // 1 MB
    unsigned short* Tg = (unsigned short*)ws;    ws += (size_t)ZA*8192*2;            // 50.3 MB
    unsigned short* part = (unsigned short*)ws;  ws += (size_t)ZB*NKC*NATOMS*128*2;   // 25.2 MB

    hipMemsetAsync(d_out, 0, (size_t)out_size*sizeof(float), stream);

    dim3 gt(24, 32, 2);
    dim3 gf(ZB, NKC);
    dim3 gd(96, ZB);
    // prep: rWo bf16 permute (both layers) + R-tables (both layers)
    k_prep<<<512, 256, 0, stream>>>(rWo[0], rWo[1], Bp);
    k_table<<<dim3(TABN+1, 2), 64, 0, stream>>>(rW1[0], rb1[0], rW2[0], rb2[0],
                                                rW1[1], rb1[1], rW2[1], rb2[1], Rtab);
    // layer 0 (encode fused into tmpB)
    k_tmpB<<<gt, 256, 0, stream>>>(nullptr, nullptr, features, W_bio, b_bio, W_ch, b_ch,
                                   mask, Bp, Tg);
    k_fused<<<gf, 256, 0, stream>>>(geometry, Rtab, Tg, part);
    k_reduceB<<<gd, 256, 0, stream>>>(part, mask, fAb, fAc);
    // layer 1
    k_tmpB<<<gt, 256, 0, stream>>>(fAb, fAc, nullptr, W_bio, b_bio, W_ch, b_ch,
                                   mask, Bp + 262144, Tg);
    k_fused<<<gf, 256, 0, stream>>>(geometry, Rtab + TABSTRIDE, Tg, part);
    // fused tail: reduce(layer1) + head + sum (atomics into zeroed out)
    k_head2<<<NATOMS, 512, 0, stream>>>(part, mask, fW1, fb1, fW2, fb2, (float*)d_out);
}

// Round 17
// 227.807 us; speedup vs baseline: 1.1175x; 1.1175x over previous
//
#include <hip/hip_runtime.h>
#include <math.h>

#define ZB 16
#define NATOMS 192
#define NBAS 40
#define ZA (ZB*NATOMS)       // 3072
#define NKC 32               // K-chunks in contraction
#define TABN 8192            // R-table samples over u in [0,40] (nearest-neighbor)
#define TABSTRIDE ((TABN+1)*64)

typedef __attribute__((ext_vector_type(4))) float f32x4;
typedef __attribute__((ext_vector_type(8))) short bf16x8;

__device__ __forceinline__ unsigned short f2bf(float x){
    union { float f; unsigned u; } v; v.f = x;
    unsigned r = v.u + 0x7FFFu + ((v.u >> 16) & 1u);
    return (unsigned short)(r >> 16);
}
__device__ __forceinline__ unsigned short f2bf_t(float x){
    union { float f; unsigned u; } v; v.f = x;
    return (unsigned short)(v.u >> 16);
}
__device__ __forceinline__ float bf2f(unsigned short u){
    union { unsigned u; float f; } v; v.u = ((unsigned)u) << 16; return v.f;
}
__device__ __forceinline__ float sspf_lean(float x){
    float e = __builtin_amdgcn_exp2f(7.2134752f*x);
    float l = __builtin_amdgcn_logf(1.f + e);
    return fmaf(l, 0.13862944f, -0.13862944f);
}
__device__ __forceinline__ float spf_act(float x){
    float t = 7.2134752f*x;
    float tc = fminf(t, 126.f);
    float e = __builtin_amdgcn_exp2f(tc);
    float l = __builtin_amdgcn_logf(1.f + e);
    float r = l*0.13862944f;
    return (t > 126.f) ? x : r;
}

// ---------------- prep: Bp[layer][(j*64+h)*64 + i] = bf16(rWo[h][j][i]) — both layers
__global__ void k_prep(const float* __restrict__ rWo_0, const float* __restrict__ rWo_1,
                       unsigned short* __restrict__ Bp){
    int idx = blockIdx.x*256 + threadIdx.x;
    for (int i = idx; i < 2*262144; i += gridDim.x*256){
        int l = i >> 18, r = i & 262143;
        int n = r >> 6, ii = r & 63;       // n = j*64+h
        int j = n >> 6, h = n & 63;
        const float* src = l ? rWo_1 : rWo_0;
        Bp[i] = f2bf(src[(h*64 + j)*64 + ii]);
    }
}

// ---------------- R-table: Rtab[l][i*64+h] = bf16(R(u_i)[h]), u_i = i*(40/8192).
// Full-precision fp32 radial MLP per sample.
__global__ void k_table(const float* __restrict__ rW1_0, const float* __restrict__ rb1_0,
                        const float* __restrict__ rW2_0, const float* __restrict__ rb2_0,
                        const float* __restrict__ rW1_1, const float* __restrict__ rb1_1,
                        const float* __restrict__ rW2_1, const float* __restrict__ rb2_1,
                        unsigned short* __restrict__ Rtab){
    __shared__ float h1S[64];
    int i = blockIdx.x;            // [0, 8193)
    int l = blockIdx.y;
    int h = threadIdx.x;           // 64
    const float* rW1 = l ? rW1_1 : rW1_0;
    const float* rb1 = l ? rb1_1 : rb1_0;
    const float* rW2 = l ? rW2_1 : rW2_0;
    const float* rb2 = l ? rb2_1 : rb2_0;
    float u = (float)i * 0.0048828125f;         // 40/8192
    int k0 = (int)u;
    float fr = u - (float)k0;
    float cs = __cosf(fr * 1.57079632679489662f);
    float c0 = cs*cs, c1 = 1.f - c0;
    if (k0   >= NBAS) c0 = 0.f;
    if (k0+1 >= NBAS) c1 = 0.f;
    int kk0 = min(k0, NBAS-1)*64, kk1 = min(k0+1, NBAS-1)*64;
    h1S[h] = sspf_lean(c0*rW1[kk0+h] + c1*rW1[kk1+h] + rb1[h]);
    __syncthreads();
    float acc = rb2[h];
    #pragma unroll 8
    for (int hin = 0; hin < 64; hin++) acc += h1S[hin]*rW2[hin*64 + h];
    Rtab[(size_t)l*TABSTRIDE + i*64 + h] = f2bf(sspf_lean(acc));
}

// ---------------- tmp GEMM bf16 MFMA: Tg[m][s*4096 + j*64 + h] = (f_s[m] @ rWo[h][j][:]) * mask*c
__global__ __launch_bounds__(256,2) void k_tmpB(
    const unsigned short* __restrict__ fb, const unsigned short* __restrict__ fc,
    const float* __restrict__ feat,
    const float* __restrict__ Wb, const float* __restrict__ bb,
    const float* __restrict__ Wc, const float* __restrict__ bc,
    const float* __restrict__ mask, const unsigned short* __restrict__ Bp,
    unsigned short* __restrict__ Tg)
{
    __shared__ unsigned short sm[18432];   // As[128*72] | Bs[128*72]; Cs overlays all
    __shared__ float msk[128];
    __shared__ float featS[128*8];
    __shared__ float WbS[7*64];
    __shared__ float bbS[64], WcS[64], bcS[64];
    unsigned short* As = sm;
    unsigned short* Bs = sm + 9216;
    unsigned short* Cs = sm;

    int tid = threadIdx.x;
    int m0 = blockIdx.x*128, n0 = blockIdx.y*128, s = blockIdx.z;
    int lane = tid & 63, w = tid >> 6, q = lane >> 4, l15 = lane & 15;
    int wm = w & 1, wn = w >> 1;

    if (feat){
        #pragma unroll
        for (int it = 0; it < 4; it++){
            int idx = tid + it*256;            // 1024 floats
            featS[idx] = feat[(size_t)m0*8 + idx];
        }
        for (int i = tid; i < 448; i += 256) WbS[i] = Wb[i];   // 7x64, strided
        if (tid < 64){ bbS[tid] = bb[tid]; WcS[tid] = Wc[tid]; bcS[tid] = bc[tid]; }
        __syncthreads();
        #pragma unroll
        for (int it = 0; it < 32; it++){
            int idx = tid + it*256;            // 8192
            int r = idx >> 6, e = idx & 63;
            float acc;
            if (s == 0){
                acc = bbS[e];
                #pragma unroll
                for (int c = 0; c < 7; c++) acc += featS[r*8+c]*WbS[c*64+e];
            } else {
                acc = bcS[e] + featS[r*8+7]*WcS[e];
            }
            As[r*72 + e] = f2bf(acc);
        }
    } else {
        const unsigned short* f = s ? fc : fb;
        #pragma unroll
        for (int it = 0; it < 4; it++){
            int idx = tid + it*256;            // 1024 uint4
            int r = idx >> 3, c8 = idx & 7;
            *(uint4*)(As + r*72 + c8*8) = *(const uint4*)(f + (size_t)(m0 + r)*64 + c8*8);
        }
    }
    // B-staging: pure uint4 copies from pre-converted Bp rows
    #pragma unroll
    for (int it = 0; it < 4; it++){
        int idx = tid + it*256;                // 1024 uint4
        int r = idx >> 3, c8 = idx & 7;
        *(uint4*)(Bs + r*72 + c8*8) = *(const uint4*)(Bp + (size_t)(n0 + r)*64 + c8*8);
    }
    if (tid < 128) msk[tid] = mask[m0 + tid] * 0.07216878364870322f;
    __syncthreads();

    f32x4 acc[16];
    #pragma unroll
    for (int i = 0; i < 16; i++) acc[i] = (f32x4){0.f,0.f,0.f,0.f};
    #pragma unroll
    for (int kc = 0; kc < 2; kc++){
        bf16x8 af[4];
        #pragma unroll
        for (int mt = 0; mt < 4; mt++)
            af[mt] = *(const bf16x8*)(As + (wm*64 + mt*16 + l15)*72 + kc*32 + q*8);
        #pragma unroll
        for (int nt = 0; nt < 4; nt++){
            bf16x8 bf_ = *(const bf16x8*)(Bs + (wn*64 + nt*16 + l15)*72 + kc*32 + q*8);
            #pragma unroll
            for (int mt = 0; mt < 4; mt++)
                acc[mt*4+nt] = __builtin_amdgcn_mfma_f32_16x16x32_bf16(af[mt], bf_, acc[mt*4+nt], 0, 0, 0);
        }
    }
    __syncthreads();   // all As/Bs reads done -> overlay Cs
    #pragma unroll
    for (int mt = 0; mt < 4; mt++)
        #pragma unroll
        for (int nt = 0; nt < 4; nt++)
            #pragma unroll
            for (int e = 0; e < 4; e++){
                int row2 = mt*16 + q*4 + e;
                float v = acc[mt*4+nt][e] * msk[wm*64 + row2];
                Cs[w*4608 + row2*72 + nt*16 + l15] = f2bf_t(v);
            }
    __syncthreads();
    #pragma unroll
    for (int it = 0; it < 8; it++){
        int flat = lane + it*64;               // [0,512)
        int rr = flat >> 3, c8 = flat & 7;
        uint4 v = *(const uint4*)(Cs + w*4608 + rr*72 + c8*8);
        size_t dst = (size_t)(m0 + wm*64 + rr)*8192 + s*4096 + n0 + wn*64 + c8*8;
        *(uint4*)(Tg + dst) = v;
    }
}

// ---------------- FUSED contraction, nearest-neighbor R-table + 1-iter gather prefetch.
// Per b: per-lane r -> nearest idx -> six 16B gathers == the bf16 A-fragments directly.
// Gathers for b+1 issued before barrier(b) -> hidden by contraction(b).
__global__ __launch_bounds__(256,2) void k_fused(
    const float* __restrict__ geom,
    const unsigned short* __restrict__ Rtab,
    const unsigned short* __restrict__ Tc,
    unsigned short* __restrict__ part)
{
    __shared__ unsigned short smB[2][128*72];   // 36864 B (epilogue staging reuses this)

    int tid = threadIdx.x;
    int z = blockIdx.x, kc = blockIdx.y;
    int lane = tid & 63, w = tid >> 6, q = lane >> 4, l15 = lane & 15;
    int a_r = tid >> 3, c8 = tid & 7;

    float gaxr[3], gayr[3], gazr[3];
    #pragma unroll
    for (int mt = 0; mt < 3; mt++){
        int ar = w*48 + mt*16 + l15;
        const float* gp = geom + (size_t)(z*NATOMS + ar)*3;
        gaxr[mt] = gp[0]; gayr[mt] = gp[1]; gazr[mt] = gp[2];
    }

    const size_t Tbase = (size_t)z*NATOMS*8192;
    uint4 rbv[4];
    {
        const unsigned short* Bb = Tc + Tbase + (size_t)(kc*6)*8192;
        #pragma unroll
        for (int r = 0; r < 4; r++) rbv[r] = *(const uint4*)(Bb + (size_t)(a_r + 32*r)*64 + c8*8);
    }

    f32x4 acc[24];
    #pragma unroll
    for (int i = 0; i < 24; i++) acc[i] = (f32x4){0.f,0.f,0.f,0.f};

    uint4 G[2][6];   // A-fragment gathers, double-buffered across b
    // prologue: gathers for b0
    {
        const float* gb = geom + (size_t)(z*NATOMS + kc*6)*3;
        float gbx = gb[0], gby = gb[1], gbz = gb[2];
        #pragma unroll
        for (int mt = 0; mt < 3; mt++){
            float dx = gaxr[mt]-gbx, dy = gayr[mt]-gby, dz = gazr[mt]-gbz;
            float r = sqrtf(dx*dx + dy*dy + dz*dz);
            float fu = fminf(r * 798.72f, 8192.0f);
            int idn = (int)(fu + 0.5f) * 64;
            #pragma unroll
            for (int kq = 0; kq < 2; kq++)
                G[0][kq*3+mt] = *(const uint4*)(Rtab + idn + kq*32 + q*8);
        }
    }

    #pragma unroll
    for (int i = 0; i < 6; i++){
        const int buf = i & 1;
        int b = kc*6 + i;
        // commit prefetched B tile (buf last read in contraction(i-2), before barrier(i-1))
        #pragma unroll
        for (int r = 0; r < 4; r++) *(uint4*)(smB[buf] + (a_r + 32*r)*72 + c8*8) = rbv[r];
        if (i < 5){
            const unsigned short* Bb = Tc + Tbase + (size_t)(b+1)*8192;
            #pragma unroll
            for (int r = 0; r < 4; r++) rbv[r] = *(const uint4*)(Bb + (size_t)(a_r + 32*r)*64 + c8*8);
            // prefetch gathers for b+1 (consumed after NEXT barrier)
            const float* gb = geom + (size_t)(z*NATOMS + b + 1)*3;
            float gbx = gb[0], gby = gb[1], gbz = gb[2];
            #pragma unroll
            for (int mt = 0; mt < 3; mt++){
                float dx = gaxr[mt]-gbx, dy = gayr[mt]-gby, dz = gazr[mt]-gbz;
                float r = sqrtf(dx*dx + dy*dy + dz*dz);
                float fu = fminf(r * 798.72f, 8192.0f);
                int idn = (int)(fu + 0.5f) * 64;
                #pragma unroll
                for (int kq = 0; kq < 2; kq++)
                    G[buf^1][kq*3+mt] = *(const uint4*)(Rtab + idn + kq*32 + q*8);
            }
        }
        __syncthreads();       // smB[buf] visible to all waves
        #pragma unroll
        for (int kq = 0; kq < 2; kq++){
            #pragma unroll
            for (int mt = 0; mt < 3; mt++){
                bf16x8 af = *(bf16x8*)&G[buf][kq*3+mt];
                #pragma unroll
                for (int nt = 0; nt < 8; nt++){
                    bf16x8 bb = *(const bf16x8*)(smB[buf] + (nt*16 + l15)*72 + kq*32 + q*8);
                    acc[mt*8+nt] = __builtin_amdgcn_mfma_f32_16x16x32_bf16(af, bb, acc[mt*8+nt], 0, 0, 0);
                }
            }
        }
    }
    // epilogue: LDS-staged contiguous write of part tile (192x128 bf16), staging over smB
    unsigned short* stg = (unsigned short*)smB;   // row stride 136 shorts (26112 B <= 36864)
    #pragma unroll
    for (int half = 0; half < 2; half++){
        __syncthreads();
        if ((w >> 1) == half){
            int wl = w & 1;
            #pragma unroll
            for (int mt = 0; mt < 3; mt++)
                #pragma unroll
                for (int nt = 0; nt < 8; nt++)
                    #pragma unroll
                    for (int e = 0; e < 4; e++){
                        int row = wl*48 + mt*16 + q*4 + e;      // [0,96)
                        stg[row*136 + nt*16 + l15] = f2bf_t(acc[mt*8+nt][e]);
                    }
        }
        __syncthreads();
        unsigned short* gdst = part + ((size_t)(z*NKC + kc)*NATOMS + half*96)*128;
        #pragma unroll
        for (int it = 0; it < 6; it++){
            int flat = tid + it*256;          // [0,1536) uint4s
            int row = flat >> 4, cc = flat & 15;
            uint4 v = *(const uint4*)(stg + row*136 + cc*8);
            *(uint4*)(gdst + row*128 + cc*8) = v;
        }
    }
}

// ---------------- reduce partials + sp + mask -> bf16 next features (layer 0 only)
__global__ void k_reduceB(const unsigned short* __restrict__ part, const float* __restrict__ mask,
                          unsigned short* __restrict__ fb, unsigned short* __restrict__ fc){
    int zl = blockIdx.y;
    int idx = blockIdx.x*256 + threadIdx.x;    // [0, 24576)
    int a = idx >> 7, j2 = idx & 127;
    const unsigned short* p = part + ((size_t)(zl*NKC)*NATOMS + a)*128 + j2;
    float s = 0.f;
    #pragma unroll
    for (int c = 0; c < NKC; c++) s += bf2f(p[(size_t)c*NATOMS*128]);
    int rowg = zl*NATOMS + a;
    float v = spf_act(s) * mask[rowg];
    if (j2 < 64) fb[rowg*64 + j2] = f2bf(v);
    else         fc[rowg*64 + j2 - 64] = f2bf(v);
}

// ---------------- fused tail: reduce(layer1) + sp + mask + h1 + BN1 + leaky + h2 + BN2
// + leaky + mask + atom-sum (atomicAdd into zeroed out). One block per atom, 512 thr.
__global__ __launch_bounds__(512) void k_head2(
    const unsigned short* __restrict__ part, const float* __restrict__ mask,
    const float* __restrict__ fW1, const float* __restrict__ fb1,
    const float* __restrict__ fW2, const float* __restrict__ fb2,
    float* __restrict__ out)
{
    __shared__ float X[2048];
    __shared__ float red[16];
    __shared__ float stats[2];
    int a = blockIdx.x, tid = threadIdx.x;     // 512 threads = 8 waves
    int lane = tid & 63, w = tid >> 6;

    // reduce part over kc -> features X[z*128 + j2]
    #pragma unroll
    for (int i = 0; i < 4; i++){
        int idx = tid + i*512; int z = idx >> 7, j2 = idx & 127;
        const unsigned short* p = part + ((size_t)(z*NKC)*NATOMS + a)*128 + j2;
        float s = 0.f;
        #pragma unroll
        for (int c = 0; c < NKC; c++) s += bf2f(p[(size_t)c*NATOMS*128]);
        X[idx] = spf_act(s) * mask[z*NATOMS + a];
    }
    __syncthreads();
    // h1: one float4 output per thread (512 x 4 = 2048)
    f32x4 v; float s, ss;
    {
        int z = tid >> 5, k4 = (tid & 31)*4;
        f32x4 acc = { fb1[k4], fb1[k4+1], fb1[k4+2], fb1[k4+3] };
        #pragma unroll 4
        for (int c = 0; c < 128; c++){
            float xv = X[z*128 + c];
            float4 wv = *(const float4*)(fW1 + (size_t)c*128 + k4);
            acc[0] += xv*wv.x; acc[1] += xv*wv.y; acc[2] += xv*wv.z; acc[3] += xv*wv.w;
        }
        v = acc;
        s = acc[0]+acc[1]+acc[2]+acc[3];
        ss = acc[0]*acc[0]+acc[1]*acc[1]+acc[2]*acc[2]+acc[3]*acc[3];
    }
    for (int off = 32; off; off >>= 1){ s += __shfl_down(s, off); ss += __shfl_down(ss, off); }
    if (!lane){ red[w] = s; red[8+w] = ss; }
    __syncthreads();
    if (!tid){
        float S = 0.f, SS = 0.f;
        #pragma unroll
        for (int i = 0; i < 8; i++){ S += red[i]; SS += red[8+i]; }
        float m = S*(1.f/2048.f), var = SS*(1.f/2048.f) - m*m;
        stats[0] = m; stats[1] = rsqrtf(var + 1e-5f);
    }
    __syncthreads();
    float m1 = stats[0], inv1 = stats[1];
    {
        f32x4 t;
        #pragma unroll
        for (int e = 0; e < 4; e++){
            float x = (v[e]-m1)*inv1;
            t[e] = (x > 0.f) ? x : 0.2f*x;
        }
        *(f32x4*)(X + tid*4) = t;
    }
    __syncthreads();
    // h2: one output per thread (512)
    float u;
    {
        int z = tid >> 5, j = tid & 31;
        float acc = fb2[j];
        #pragma unroll 8
        for (int k = 0; k < 128; k++) acc += X[z*128 + k]*fW2[k*32 + j];
        u = acc; s = acc; ss = acc*acc;
    }
    for (int off = 32; off; off >>= 1){ s += __shfl_down(s, off); ss += __shfl_down(ss, off); }
    if (!lane){ red[w] = s; red[8+w] = ss; }
    __syncthreads();
    if (!tid){
        float S = 0.f, SS = 0.f;
        #pragma unroll
        for (int i = 0; i < 8; i++){ S += red[i]; SS += red[8+i]; }
        float m = S*(1.f/512.f), var = SS*(1.f/512.f) - m*m;
        stats[0] = m; stats[1] = rsqrtf(var + 1e-5f);
    }
    __syncthreads();
    float m2 = stats[0], inv2 = stats[1];
    {
        int z = tid >> 5, j = tid & 31;
        float x = (u-m2)*inv2;
        x = (x > 0.f) ? x : 0.2f*x;
        x *= mask[z*NATOMS + a];
        atomicAdd(&out[z*32 + j], x);
    }
}

extern "C" void kernel_launch(void* const* d_in, const int* in_sizes, int n_in,
                              void* d_out, int out_size, void* d_ws, size_t ws_size,
                              hipStream_t stream){
    const float* features = (const float*)d_in[0];
    const float* geometry = (const float*)d_in[1];
    const float* mask     = (const float*)d_in[2];
    const float* W_bio    = (const float*)d_in[3];
    const float* b_bio    = (const float*)d_in[4];
    const float* W_ch     = (const float*)d_in[5];
    const float* b_ch     = (const float*)d_in[6];
    const float* rW1[2] = {(const float*)d_in[7],  (const float*)d_in[12]};
    const float* rb1[2] = {(const float*)d_in[8],  (const float*)d_in[13]};
    const float* rW2[2] = {(const float*)d_in[9],  (const float*)d_in[14]};
    const float* rb2[2] = {(const float*)d_in[10], (const float*)d_in[15]};
    const float* rWo[2] = {(const float*)d_in[11], (const float*)d_in[16]};
    const float* fW1 = (const float*)d_in[17];
    const float* fb1 = (const float*)d_in[18];
    const float* fW2 = (const float*)d_in[19];
    const float* fb2 = (const float*)d_in[20];

    char* ws = (char*)d_ws;
    unsigned short* fAb = (unsigned short*)ws;   ws += (size_t)ZA*64*2;
    unsigned short* fAc = (unsigned short*)ws;   ws += (size_t)ZA*64*2;
    unsigned short* Rtab = (unsigned short*)ws;  ws += (size_t)2*TABSTRIDE*2;        // 2.1 MB
    unsigned short* Bp = (unsigned short*)ws;    ws += (size_t)2*262144*2;           // 1 MB
    unsigned short* Tg = (unsigned short*)ws;    ws += (size_t)ZA*8192*2;            // 50.3 MB
    unsigned short* part = (unsigned short*)ws;  ws += (size_t)ZB*NKC*NATOMS*128*2;   // 25.2 MB

    hipMemsetAsync(d_out, 0, (size_t)out_size*sizeof(float), stream);

    dim3 gt(24, 32, 2);
    dim3 gf(ZB, NKC);
    dim3 gd(96, ZB);
    // prep: rWo bf16 permute (both layers) + R-tables (both layers)
    k_prep<<<512, 256, 0, stream>>>(rWo[0], rWo[1], Bp);
    k_table<<<dim3(TABN+1, 2), 64, 0, stream>>>(rW1[0], rb1[0], rW2[0], rb2[0],
                                                rW1[1], rb1[1], rW2[1], rb2[1], Rtab);
    // layer 0 (encode fused into tmpB)
    k_tmpB<<<gt, 256, 0, stream>>>(nullptr, nullptr, features, W_bio, b_bio, W_ch, b_ch,
                                   mask, Bp, Tg);
    k_fused<<<gf, 256, 0, stream>>>(geometry, Rtab, Tg, part);
    k_reduceB<<<gd, 256, 0, stream>>>(part, mask, fAb, fAc);
    // layer 1
    k_tmpB<<<gt, 256, 0, stream>>>(fAb, fAc, nullptr, W_bio, b_bio, W_ch, b_ch,
                                   mask, Bp + 262144, Tg);
    k_fused<<<gf, 256, 0, stream>>>(geometry, Rtab + TABSTRIDE, Tg, part);
    // fused tail: reduce(layer1) + head + sum (atomics into zeroed out)
    k_head2<<<NATOMS, 512, 0, stream>>>(part, mask, fW1, fb1, fW2, fb2, (float*)d_out);
}

// Round 18
// 226.274 us; speedup vs baseline: 1.1251x; 1.0068x over previous
//
#include <hip/hip_runtime.h>
#include <math.h>

#define ZB 16
#define NATOMS 192
#define NBAS 40
#define ZA (ZB*NATOMS)       // 3072
#define NKC 32               // K-chunks in contraction
#define TABN 8192            // R-table samples over u in [0,40] (nearest-neighbor)
#define TABSTRIDE ((TABN+1)*64)

typedef __attribute__((ext_vector_type(4))) float f32x4;
typedef __attribute__((ext_vector_type(8))) short bf16x8;

__device__ __forceinline__ unsigned short f2bf(float x){
    union { float f; unsigned u; } v; v.f = x;
    unsigned r = v.u + 0x7FFFu + ((v.u >> 16) & 1u);
    return (unsigned short)(r >> 16);
}
__device__ __forceinline__ unsigned short f2bf_t(float x){
    union { float f; unsigned u; } v; v.f = x;
    return (unsigned short)(v.u >> 16);
}
__device__ __forceinline__ float bf2f(unsigned short u){
    union { unsigned u; float f; } v; v.u = ((unsigned)u) << 16; return v.f;
}
__device__ __forceinline__ float bits2f(unsigned u){
    union { unsigned u; float f; } v; v.u = u; return v.f;
}
__device__ __forceinline__ float sspf_lean(float x){
    float e = __builtin_amdgcn_exp2f(7.2134752f*x);
    float l = __builtin_amdgcn_logf(1.f + e);
    return fmaf(l, 0.13862944f, -0.13862944f);
}
__device__ __forceinline__ float spf_act(float x){
    float t = 7.2134752f*x;
    float tc = fminf(t, 126.f);
    float e = __builtin_amdgcn_exp2f(tc);
    float l = __builtin_amdgcn_logf(1.f + e);
    float r = l*0.13862944f;
    return (t > 126.f) ? x : r;
}

// ---------------- prep: Bp[layer][(j*64+h)*64 + i] = bf16(rWo[h][j][i]) — both layers.
// Also zeroes d_out (replaces the memset dispatch).
__global__ void k_prep(const float* __restrict__ rWo_0, const float* __restrict__ rWo_1,
                       unsigned short* __restrict__ Bp, float* __restrict__ out){
    int idx = blockIdx.x*256 + threadIdx.x;
    if (blockIdx.x == 0){
        for (int i = threadIdx.x; i < 512; i += 256) out[i] = 0.f;
    }
    for (int i = idx; i < 2*262144; i += gridDim.x*256){
        int l = i >> 18, r = i & 262143;
        int n = r >> 6, ii = r & 63;       // n = j*64+h
        int j = n >> 6, h = n & 63;
        const float* src = l ? rWo_1 : rWo_0;
        Bp[i] = f2bf(src[(h*64 + j)*64 + ii]);
    }
}

// ---------------- R-table: Rtab[l][i*64+h] = bf16(R(u_i)[h]), u_i = i*(40/8192).
// 256-thread blocks, 4 samples each; full-precision fp32 radial MLP per sample.
__global__ void k_table(const float* __restrict__ rW1_0, const float* __restrict__ rb1_0,
                        const float* __restrict__ rW2_0, const float* __restrict__ rb2_0,
                        const float* __restrict__ rW1_1, const float* __restrict__ rb1_1,
                        const float* __restrict__ rW2_1, const float* __restrict__ rb2_1,
                        unsigned short* __restrict__ Rtab){
    __shared__ float h1S[4][64];
    int l = blockIdx.y;
    int tid = threadIdx.x;
    int sIdx = tid >> 6, h = tid & 63;
    int i = blockIdx.x*4 + sIdx;           // [0, 8193)
    const float* rW1 = l ? rW1_1 : rW1_0;
    const float* rb1 = l ? rb1_1 : rb1_0;
    const float* rW2 = l ? rW2_1 : rW2_0;
    const float* rb2 = l ? rb2_1 : rb2_0;
    if (i <= TABN){
        float u = (float)i * 0.0048828125f;     // 40/8192
        int k0 = (int)u;
        float fr = u - (float)k0;
        float cs = __cosf(fr * 1.57079632679489662f);
        float c0 = cs*cs, c1 = 1.f - c0;
        if (k0   >= NBAS) c0 = 0.f;
        if (k0+1 >= NBAS) c1 = 0.f;
        int kk0 = min(k0, NBAS-1)*64, kk1 = min(k0+1, NBAS-1)*64;
        h1S[sIdx][h] = sspf_lean(c0*rW1[kk0+h] + c1*rW1[kk1+h] + rb1[h]);
    }
    __syncthreads();
    if (i <= TABN){
        float acc = rb2[h];
        #pragma unroll 8
        for (int hin = 0; hin < 64; hin++) acc += h1S[sIdx][hin]*rW2[hin*64 + h];
        Rtab[(size_t)l*TABSTRIDE + i*64 + h] = f2bf(sspf_lean(acc));
    }
}

// ---------------- tmp GEMM bf16 MFMA: Tg[m][s*4096 + j*64 + h] = (f_s[m] @ rWo[h][j][:]) * mask*c
__global__ __launch_bounds__(256,2) void k_tmpB(
    const unsigned short* __restrict__ fb, const unsigned short* __restrict__ fc,
    const float* __restrict__ feat,
    const float* __restrict__ Wb, const float* __restrict__ bb,
    const float* __restrict__ Wc, const float* __restrict__ bc,
    const float* __restrict__ mask, const unsigned short* __restrict__ Bp,
    unsigned short* __restrict__ Tg)
{
    __shared__ unsigned short sm[18432];   // As[128*72] | Bs[128*72]; Cs overlays all
    __shared__ float msk[128];
    __shared__ float featS[128*8];
    __shared__ float WbS[7*64];
    __shared__ float bbS[64], WcS[64], bcS[64];
    unsigned short* As = sm;
    unsigned short* Bs = sm + 9216;
    unsigned short* Cs = sm;

    int tid = threadIdx.x;
    int m0 = blockIdx.x*128, n0 = blockIdx.y*128, s = blockIdx.z;
    int lane = tid & 63, w = tid >> 6, q = lane >> 4, l15 = lane & 15;
    int wm = w & 1, wn = w >> 1;

    if (feat){
        #pragma unroll
        for (int it = 0; it < 4; it++){
            int idx = tid + it*256;            // 1024 floats
            featS[idx] = feat[(size_t)m0*8 + idx];
        }
        for (int i = tid; i < 448; i += 256) WbS[i] = Wb[i];   // 7x64, strided
        if (tid < 64){ bbS[tid] = bb[tid]; WcS[tid] = Wc[tid]; bcS[tid] = bc[tid]; }
        __syncthreads();
        #pragma unroll
        for (int it = 0; it < 32; it++){
            int idx = tid + it*256;            // 8192
            int r = idx >> 6, e = idx & 63;
            float acc;
            if (s == 0){
                acc = bbS[e];
                #pragma unroll
                for (int c = 0; c < 7; c++) acc += featS[r*8+c]*WbS[c*64+e];
            } else {
                acc = bcS[e] + featS[r*8+7]*WcS[e];
            }
            As[r*72 + e] = f2bf(acc);
        }
    } else {
        const unsigned short* f = s ? fc : fb;
        #pragma unroll
        for (int it = 0; it < 4; it++){
            int idx = tid + it*256;            // 1024 uint4
            int r = idx >> 3, c8 = idx & 7;
            *(uint4*)(As + r*72 + c8*8) = *(const uint4*)(f + (size_t)(m0 + r)*64 + c8*8);
        }
    }
    // B-staging: pure uint4 copies from pre-converted Bp rows
    #pragma unroll
    for (int it = 0; it < 4; it++){
        int idx = tid + it*256;                // 1024 uint4
        int r = idx >> 3, c8 = idx & 7;
        *(uint4*)(Bs + r*72 + c8*8) = *(const uint4*)(Bp + (size_t)(n0 + r)*64 + c8*8);
    }
    if (tid < 128) msk[tid] = mask[m0 + tid] * 0.07216878364870322f;
    __syncthreads();

    f32x4 acc[16];
    #pragma unroll
    for (int i = 0; i < 16; i++) acc[i] = (f32x4){0.f,0.f,0.f,0.f};
    #pragma unroll
    for (int kc = 0; kc < 2; kc++){
        bf16x8 af[4];
        #pragma unroll
        for (int mt = 0; mt < 4; mt++)
            af[mt] = *(const bf16x8*)(As + (wm*64 + mt*16 + l15)*72 + kc*32 + q*8);
        #pragma unroll
        for (int nt = 0; nt < 4; nt++){
            bf16x8 bf_ = *(const bf16x8*)(Bs + (wn*64 + nt*16 + l15)*72 + kc*32 + q*8);
            #pragma unroll
            for (int mt = 0; mt < 4; mt++)
                acc[mt*4+nt] = __builtin_amdgcn_mfma_f32_16x16x32_bf16(af[mt], bf_, acc[mt*4+nt], 0, 0, 0);
        }
    }
    __syncthreads();   // all As/Bs reads done -> overlay Cs
    #pragma unroll
    for (int mt = 0; mt < 4; mt++)
        #pragma unroll
        for (int nt = 0; nt < 4; nt++)
            #pragma unroll
            for (int e = 0; e < 4; e++){
                int row2 = mt*16 + q*4 + e;
                float v = acc[mt*4+nt][e] * msk[wm*64 + row2];
                Cs[w*4608 + row2*72 + nt*16 + l15] = f2bf_t(v);
            }
    __syncthreads();
    #pragma unroll
    for (int it = 0; it < 8; it++){
        int flat = lane + it*64;               // [0,512)
        int rr = flat >> 3, c8 = flat & 7;
        uint4 v = *(const uint4*)(Cs + w*4608 + rr*72 + c8*8);
        size_t dst = (size_t)(m0 + wm*64 + rr)*8192 + s*4096 + n0 + wn*64 + c8*8;
        *(uint4*)(Tg + dst) = v;
    }
}

// ---------------- FUSED contraction, nearest-neighbor R-table + 1-iter gather prefetch.
__global__ __launch_bounds__(256,2) void k_fused(
    const float* __restrict__ geom,
    const unsigned short* __restrict__ Rtab,
    const unsigned short* __restrict__ Tc,
    unsigned short* __restrict__ part)
{
    __shared__ unsigned short smB[2][128*72];   // 36864 B (epilogue staging reuses this)

    int tid = threadIdx.x;
    int z = blockIdx.x, kc = blockIdx.y;
    int lane = tid & 63, w = tid >> 6, q = lane >> 4, l15 = lane & 15;
    int a_r = tid >> 3, c8 = tid & 7;

    float gaxr[3], gayr[3], gazr[3];
    #pragma unroll
    for (int mt = 0; mt < 3; mt++){
        int ar = w*48 + mt*16 + l15;
        const float* gp = geom + (size_t)(z*NATOMS + ar)*3;
        gaxr[mt] = gp[0]; gayr[mt] = gp[1]; gazr[mt] = gp[2];
    }

    const size_t Tbase = (size_t)z*NATOMS*8192;
    uint4 rbv[4];
    {
        const unsigned short* Bb = Tc + Tbase + (size_t)(kc*6)*8192;
        #pragma unroll
        for (int r = 0; r < 4; r++) rbv[r] = *(const uint4*)(Bb + (size_t)(a_r + 32*r)*64 + c8*8);
    }

    f32x4 acc[24];
    #pragma unroll
    for (int i = 0; i < 24; i++) acc[i] = (f32x4){0.f,0.f,0.f,0.f};

    uint4 G[2][6];   // A-fragment gathers, double-buffered across b
    {
        const float* gb = geom + (size_t)(z*NATOMS + kc*6)*3;
        float gbx = gb[0], gby = gb[1], gbz = gb[2];
        #pragma unroll
        for (int mt = 0; mt < 3; mt++){
            float dx = gaxr[mt]-gbx, dy = gayr[mt]-gby, dz = gazr[mt]-gbz;
            float r = sqrtf(dx*dx + dy*dy + dz*dz);
            float fu = fminf(r * 798.72f, 8192.0f);
            int idn = (int)(fu + 0.5f) * 64;
            #pragma unroll
            for (int kq = 0; kq < 2; kq++)
                G[0][kq*3+mt] = *(const uint4*)(Rtab + idn + kq*32 + q*8);
        }
    }

    #pragma unroll
    for (int i = 0; i < 6; i++){
        const int buf = i & 1;
        int b = kc*6 + i;
        #pragma unroll
        for (int r = 0; r < 4; r++) *(uint4*)(smB[buf] + (a_r + 32*r)*72 + c8*8) = rbv[r];
        if (i < 5){
            const unsigned short* Bb = Tc + Tbase + (size_t)(b+1)*8192;
            #pragma unroll
            for (int r = 0; r < 4; r++) rbv[r] = *(const uint4*)(Bb + (size_t)(a_r + 32*r)*64 + c8*8);
            const float* gb = geom + (size_t)(z*NATOMS + b + 1)*3;
            float gbx = gb[0], gby = gb[1], gbz = gb[2];
            #pragma unroll
            for (int mt = 0; mt < 3; mt++){
                float dx = gaxr[mt]-gbx, dy = gayr[mt]-gby, dz = gazr[mt]-gbz;
                float r = sqrtf(dx*dx + dy*dy + dz*dz);
                float fu = fminf(r * 798.72f, 8192.0f);
                int idn = (int)(fu + 0.5f) * 64;
                #pragma unroll
                for (int kq = 0; kq < 2; kq++)
                    G[buf^1][kq*3+mt] = *(const uint4*)(Rtab + idn + kq*32 + q*8);
            }
        }
        __syncthreads();       // smB[buf] visible to all waves
        #pragma unroll
        for (int kq = 0; kq < 2; kq++){
            #pragma unroll
            for (int mt = 0; mt < 3; mt++){
                bf16x8 af = *(bf16x8*)&G[buf][kq*3+mt];
                #pragma unroll
                for (int nt = 0; nt < 8; nt++){
                    bf16x8 bb = *(const bf16x8*)(smB[buf] + (nt*16 + l15)*72 + kq*32 + q*8);
                    acc[mt*8+nt] = __builtin_amdgcn_mfma_f32_16x16x32_bf16(af, bb, acc[mt*8+nt], 0, 0, 0);
                }
            }
        }
    }
    // epilogue: LDS-staged contiguous write of part tile (192x128 bf16), staging over smB
    unsigned short* stg = (unsigned short*)smB;   // row stride 136 shorts (26112 B <= 36864)
    #pragma unroll
    for (int half = 0; half < 2; half++){
        __syncthreads();
        if ((w >> 1) == half){
            int wl = w & 1;
            #pragma unroll
            for (int mt = 0; mt < 3; mt++)
                #pragma unroll
                for (int nt = 0; nt < 8; nt++)
                    #pragma unroll
                    for (int e = 0; e < 4; e++){
                        int row = wl*48 + mt*16 + q*4 + e;      // [0,96)
                        stg[row*136 + nt*16 + l15] = f2bf_t(acc[mt*8+nt][e]);
                    }
        }
        __syncthreads();
        unsigned short* gdst = part + ((size_t)(z*NKC + kc)*NATOMS + half*96)*128;
        #pragma unroll
        for (int it = 0; it < 6; it++){
            int flat = tid + it*256;          // [0,1536) uint4s
            int row = flat >> 4, cc = flat & 15;
            uint4 v = *(const uint4*)(stg + row*136 + cc*8);
            *(uint4*)(gdst + row*128 + cc*8) = v;
        }
    }
}

// ---------------- reduce partials + sp + mask -> bf16 next features (layer 0 only)
// vectorized: each thread reduces 8 consecutive j2 via uint4 loads.
__global__ void k_reduceB(const unsigned short* __restrict__ part, const float* __restrict__ mask,
                          unsigned short* __restrict__ fb, unsigned short* __restrict__ fc){
    int z = blockIdx.y;
    int a = blockIdx.x*16 + (threadIdx.x >> 4);
    int j2 = (threadIdx.x & 15)*8;
    const unsigned short* p = part + ((size_t)(z*NKC)*NATOMS + a)*128 + j2;
    float s[8] = {};
    #pragma unroll
    for (int c = 0; c < NKC; c++){
        uint4 v = *(const uint4*)(p + (size_t)c*NATOMS*128);
        const unsigned* vp = (const unsigned*)&v;
        #pragma unroll
        for (int d = 0; d < 4; d++){
            s[2*d]   += bits2f(vp[d] << 16);
            s[2*d+1] += bits2f(vp[d] & 0xffff0000u);
        }
    }
    int rowg = z*NATOMS + a;
    float mk = mask[rowg];
    uint4 o;
    unsigned* op = (unsigned*)&o;
    #pragma unroll
    for (int d = 0; d < 4; d++){
        unsigned lo = f2bf(spf_act(s[2*d])*mk);
        unsigned hi = f2bf(spf_act(s[2*d+1])*mk);
        op[d] = lo | (hi << 16);
    }
    if (j2 < 64) *(uint4*)(fb + (size_t)rowg*64 + j2) = o;
    else         *(uint4*)(fc + (size_t)rowg*64 + j2 - 64) = o;
}

// ---------------- fused tail: reduce(layer1) + sp + mask + h1 + BN1 + leaky + h2 + BN2
// + leaky + mask + atom-sum (atomicAdd into zeroed out). One block per atom, 512 thr.
__global__ __launch_bounds__(512) void k_head2(
    const unsigned short* __restrict__ part, const float* __restrict__ mask,
    const float* __restrict__ fW1, const float* __restrict__ fb1,
    const float* __restrict__ fW2, const float* __restrict__ fb2,
    float* __restrict__ out)
{
    __shared__ float X[2048];
    __shared__ float red[16];
    __shared__ float stats[2];
    int a = blockIdx.x, tid = threadIdx.x;     // 512 threads = 8 waves
    int lane = tid & 63, w = tid >> 6;

    // reduce part over kc -> features X[z*128 + j2] (uint2 = 4 bf16 per thread)
    {
        int z = tid >> 5, j2q = (tid & 31)*4;
        const unsigned short* p = part + ((size_t)(z*NKC)*NATOMS + a)*128 + j2q;
        float s0=0.f, s1=0.f, s2=0.f, s3=0.f;
        #pragma unroll
        for (int c = 0; c < NKC; c++){
            uint2 v = *(const uint2*)(p + (size_t)c*NATOMS*128);
            s0 += bits2f(v.x << 16); s1 += bits2f(v.x & 0xffff0000u);
            s2 += bits2f(v.y << 16); s3 += bits2f(v.y & 0xffff0000u);
        }
        float mk = mask[z*NATOMS + a];
        X[z*128 + j2q    ] = spf_act(s0)*mk;
        X[z*128 + j2q + 1] = spf_act(s1)*mk;
        X[z*128 + j2q + 2] = spf_act(s2)*mk;
        X[z*128 + j2q + 3] = spf_act(s3)*mk;
    }
    __syncthreads();
    // h1: one float4 output per thread (512 x 4 = 2048)
    f32x4 v; float s, ss;
    {
        int z = tid >> 5, k4 = (tid & 31)*4;
        f32x4 acc = { fb1[k4], fb1[k4+1], fb1[k4+2], fb1[k4+3] };
        #pragma unroll 4
        for (int c = 0; c < 128; c++){
            float xv = X[z*128 + c];
            float4 wv = *(const float4*)(fW1 + (size_t)c*128 + k4);
            acc[0] += xv*wv.x; acc[1] += xv*wv.y; acc[2] += xv*wv.z; acc[3] += xv*wv.w;
        }
        v = acc;
        s = acc[0]+acc[1]+acc[2]+acc[3];
        ss = acc[0]*acc[0]+acc[1]*acc[1]+acc[2]*acc[2]+acc[3]*acc[3];
    }
    for (int off = 32; off; off >>= 1){ s += __shfl_down(s, off); ss += __shfl_down(ss, off); }
    if (!lane){ red[w] = s; red[8+w] = ss; }
    __syncthreads();
    if (!tid){
        float S = 0.f, SS = 0.f;
        #pragma unroll
        for (int i = 0; i < 8; i++){ S += red[i]; SS += red[8+i]; }
        float m = S*(1.f/2048.f), var = SS*(1.f/2048.f) - m*m;
        stats[0] = m; stats[1] = rsqrtf(var + 1e-5f);
    }
    __syncthreads();
    float m1 = stats[0], inv1 = stats[1];
    {
        f32x4 t;
        #pragma unroll
        for (int e = 0; e < 4; e++){
            float x = (v[e]-m1)*inv1;
            t[e] = (x > 0.f) ? x : 0.2f*x;
        }
        *(f32x4*)(X + tid*4) = t;
    }
    __syncthreads();
    // h2: one output per thread (512)
    float u;
    {
        int z = tid >> 5, j = tid & 31;
        float acc = fb2[j];
        #pragma unroll 8
        for (int k = 0; k < 128; k++) acc += X[z*128 + k]*fW2[k*32 + j];
        u = acc; s = acc; ss = acc*acc;
    }
    for (int off = 32; off; off >>= 1){ s += __shfl_down(s, off); ss += __shfl_down(ss, off); }
    if (!lane){ red[w] = s; red[8+w] = ss; }
    __syncthreads();
    if (!tid){
        float S = 0.f, SS = 0.f;
        #pragma unroll
        for (int i = 0; i < 8; i++){ S += red[i]; SS += red[8+i]; }
        float m = S*(1.f/512.f), var = SS*(1.f/512.f) - m*m;
        stats[0] = m; stats[1] = rsqrtf(var + 1e-5f);
    }
    __syncthreads();
    float m2 = stats[0], inv2 = stats[1];
    {
        int z = tid >> 5, j = tid & 31;
        float x = (u-m2)*inv2;
        x = (x > 0.f) ? x : 0.2f*x;
        x *= mask[z*NATOMS + a];
        atomicAdd(&out[z*32 + j], x);
    }
}

extern "C" void kernel_launch(void* const* d_in, const int* in_sizes, int n_in,
                              void* d_out, int out_size, void* d_ws, size_t ws_size,
                              hipStream_t stream){
    const float* features = (const float*)d_in[0];
    const float* geometry = (const float*)d_in[1];
    const float* mask     = (const float*)d_in[2];
    const float* W_bio    = (const float*)d_in[3];
    const float* b_bio    = (const float*)d_in[4];
    const float* W_ch     = (const float*)d_in[5];
    const float* b_ch     = (const float*)d_in[6];
    const float* rW1[2] = {(const float*)d_in[7],  (const float*)d_in[12]};
    const float* rb1[2] = {(const float*)d_in[8],  (const float*)d_in[13]};
    const float* rW2[2] = {(const float*)d_in[9],  (const float*)d_in[14]};
    const float* rb2[2] = {(const float*)d_in[10], (const float*)d_in[15]};
    const float* rWo[2] = {(const float*)d_in[11], (const float*)d_in[16]};
    const float* fW1 = (const float*)d_in[17];
    const float* fb1 = (const float*)d_in[18];
    const float* fW2 = (const float*)d_in[19];
    const float* fb2 = (const float*)d_in[20];

    char* ws = (char*)d_ws;
    unsigned short* fAb = (unsigned short*)ws;   ws += (size_t)ZA*64*2;
    unsigned short* fAc = (unsigned short*)ws;   ws += (size_t)ZA*64*2;
    unsigned short* Rtab = (unsigned short*)ws;  ws += (size_t)2*TABSTRIDE*2;        // 2.1 MB
    unsigned short* Bp = (unsigned short*)ws;    ws += (size_t)2*262144*2;           // 1 MB
    unsigned short* Tg = (unsigned short*)ws;    ws += (size_t)ZA*8192*2;            // 50.3 MB
    unsigned short* part = (unsigned short*)ws;  ws += (size_t)ZB*NKC*NATOMS*128*2;   // 25.2 MB

    dim3 gt(24, 32, 2);
    dim3 gf(ZB, NKC);
    dim3 gr(12, ZB);
    // prep: rWo bf16 permute + d_out zero; R-tables (both layers)
    k_prep<<<512, 256, 0, stream>>>(rWo[0], rWo[1], Bp, (float*)d_out);
    k_table<<<dim3((TABN+1+3)/4, 2), 256, 0, stream>>>(rW1[0], rb1[0], rW2[0], rb2[0],
                                                       rW1[1], rb1[1], rW2[1], rb2[1], Rtab);
    // layer 0 (encode fused into tmpB)
    k_tmpB<<<gt, 256, 0, stream>>>(nullptr, nullptr, features, W_bio, b_bio, W_ch, b_ch,
                                   mask, Bp, Tg);
    k_fused<<<gf, 256, 0, stream>>>(geometry, Rtab, Tg, part);
    k_reduceB<<<gr, 256, 0, stream>>>(part, mask, fAb, fAc);
    // layer 1
    k_tmpB<<<gt, 256, 0, stream>>>(fAb, fAc, nullptr, W_bio, b_bio, W_ch, b_ch,
                                   mask, Bp + 262144, Tg);
    k_fused<<<gf, 256, 0, stream>>>(geometry, Rtab + TABSTRIDE, Tg, part);
    // fused tail: reduce(layer1) + head + sum (atomics into zeroed out)
    k_head2<<<NATOMS, 512, 0, stream>>>(part, mask, fW1, fb1, fW2, fb2, (float*)d_out);
}